// Round 17
// baseline (648.462 us; speedup 1.0000x reference)
//
#include <hip/hip_runtime.h>
#include <math.h>

static constexpr int BB   = 256;   // batch
static constexpr int IHN  = 200;   // internal tokens
static constexpr int ILN  = 6;     // internal feature dim
static constexpr int LHN  = 100;   // leaf tokens
static constexpr int EE   = 256;   // embed dim
static constexpr int FFH  = 512;   // ff hidden
static constexpr int NL   = 2;     // layers
static constexpr int GG   = 301;   // real tokens
static constexpr int GP   = 320;   // padded tokens (10 x 32)
static constexpr int MT   = BB * GP;  // 81920 total token rows

typedef unsigned short u16;
typedef short bf16x8 __attribute__((ext_vector_type(8)));
typedef float f32x4 __attribute__((ext_vector_type(4)));

#define MFMA(a, b, c) __builtin_amdgcn_mfma_f32_16x16x32_bf16((a), (b), (c), 0, 0, 0)

__device__ __forceinline__ u16 f2bf(float f) {
    union { float f; unsigned u; } v; v.f = f;
    unsigned r = v.u + 0x7FFFu + ((v.u >> 16) & 1u);
    return (u16)(r >> 16);
}

// ---------------- wave/block reduction helpers (wave = 64) ----------------
__device__ __forceinline__ float waveReduceSum(float v) {
    for (int o = 32; o > 0; o >>= 1) v += __shfl_down(v, o, 64);
    return v;
}
__device__ __forceinline__ float waveReduceMax(float v) {
    for (int o = 32; o > 0; o >>= 1) v = fmaxf(v, __shfl_down(v, o, 64));
    return v;
}
__device__ __forceinline__ float blockReduceSum(float v, float* red) {
    int lane = threadIdx.x & 63;
    int w    = threadIdx.x >> 6;
    int nw   = (blockDim.x + 63) >> 6;
    v = waveReduceSum(v);
    if (lane == 0) red[w] = v;
    __syncthreads();
    if (threadIdx.x < 64) {
        float x = (lane < nw) ? red[lane] : 0.0f;
        x = waveReduceSum(x);
        if (lane == 0) red[0] = x;
    }
    __syncthreads();
    float r = red[0];
    __syncthreads();
    return r;
}
__device__ __forceinline__ float blockReduceMax(float v, float* red) {
    int lane = threadIdx.x & 63;
    int w    = threadIdx.x >> 6;
    int nw   = (blockDim.x + 63) >> 6;
    v = waveReduceMax(v);
    if (lane == 0) red[w] = v;
    __syncthreads();
    if (threadIdx.x < 64) {
        float x = (lane < nw) ? red[lane] : -INFINITY;
        x = waveReduceMax(x);
        if (lane == 0) red[0] = x;
    }
    __syncthreads();
    float r = red[0];
    __syncthreads();
    return r;
}

// --------- staging: global -> LDS tile [rows][64] bf16, XOR-swizzled ---------
__device__ __forceinline__ void stage_swz(const u16* src, int strideShorts, int k0,
                                          u16* ldsTile, int nChunks, int wave,
                                          int nWaves, int lane)
{
    for (int c = wave; c < nChunks; c += nWaves) {
        int o = c * 1024 + lane * 16;
        int row = o >> 7;
        int cb = (o & 127) ^ ((row & 7) << 4);
        const u16* g = src + (size_t)row * strideShorts + k0 + (cb >> 1);
        __builtin_amdgcn_global_load_lds(
            (const __attribute__((address_space(1))) unsigned int*)g,
            (__attribute__((address_space(3))) unsigned int*)((char*)ldsTile + c * 1024),
            16, 0, 0);
    }
}

__device__ __forceinline__ bf16x8 lds_frag(const u16* tile, int row, int kk, int q)
{
    int cb = (kk * 64 + q * 16) ^ ((row & 7) << 4);
    return *(const bf16x8*)((const char*)tile + row * 128 + cb);
}

// ------------- prep: transpose encoder weights to bf16 [N][K] -------------
__global__ __launch_bounds__(256) void prep_kernel(
    const float* __restrict__ wq, const float* __restrict__ wk,
    const float* __restrict__ wv, const float* __restrict__ wo,
    const float* __restrict__ wf1, const float* __restrict__ wf2,
    u16* __restrict__ wT)
{
    int l = blockIdx.y / 6, m = blockIdx.y % 6;
    int idx = blockIdx.x * 256 + threadIdx.x;
    u16* dst = wT + (size_t)l * 524288;
    if (m < 4) {
        if (idx >= EE * EE) return;
        const float* src = (m == 0 ? wq : m == 1 ? wk : m == 2 ? wv : wo) + (size_t)l * EE * EE;
        int r = idx >> 8, c = idx & 255;
        dst[m * 65536 + idx] = f2bf(src[(size_t)c * EE + r]);
    } else if (m == 4) {
        if (idx >= FFH * EE) return;
        const float* src = wf1 + (size_t)l * EE * FFH;
        int r = idx >> 8, c = idx & 255;
        dst[262144 + idx] = f2bf(src[(size_t)c * FFH + r]);
    } else {
        if (idx >= EE * FFH) return;
        const float* src = wf2 + (size_t)l * FFH * EE;
        int r = idx >> 9, c = idx & 511;
        dst[393216 + idx] = f2bf(src[(size_t)c * EE + r]);
    }
}

// ---------- embed (segment version): 32 tokens/block, w2 col in regs ----------
template<int IND, int SEG, int G0>
__global__ __launch_bounds__(256) void embed_seg(
    const float* __restrict__ obs,
    const float* __restrict__ w1, const float* __restrict__ b1,
    const float* __restrict__ w2, const float* __restrict__ b2,
    float* __restrict__ h, u16* __restrict__ hb)
{
    __shared__ float xs[32][9];
    __shared__ float hid[32][33];
    int t = threadIdx.x;
    int fi0 = blockIdx.x * 32;

    for (int p = t; p < 32 * 9; p += 256) {
        int tok = p / 9, f = p % 9;
        int fi = fi0 + tok;
        int b = fi / SEG, g = G0 + fi % SEG;
        xs[tok][f] = obs[((size_t)b * GG + g) * 9 + f];
    }
    __syncthreads();

    #pragma unroll
    for (int p = 0; p < 4; p++) {
        int idx = p * 256 + t;
        int tok = idx >> 5, hcol = idx & 31;
        float a = b1[hcol];
        #pragma unroll
        for (int i = 0; i < IND; i++) a += xs[tok][i] * w1[i * 32 + hcol];
        hid[tok][hcol] = (a > 0.0f) ? a : 0.01f * a;
    }
    __syncthreads();

    float w2c[32];
    #pragma unroll
    for (int j = 0; j < 32; j++) w2c[j] = w2[j * EE + t];
    float bb = b2[t];
    for (int tok = 0; tok < 32; tok++) {
        int fi = fi0 + tok;
        int b = fi / SEG, g = G0 + fi % SEG;
        float a = bb;
        #pragma unroll
        for (int j = 0; j < 32; j++) a += hid[tok][j] * w2c[j];
        size_t o = ((size_t)b * GP + g) * EE + t;
        h[o] = a; hb[o] = f2bf(a);
    }
}

// zero the pad rows g in [GG, GP)
__global__ __launch_bounds__(256) void pad_kernel(float* __restrict__ h, u16* __restrict__ hb)
{
    int b = blockIdx.x, t = threadIdx.x;
    for (int g = GG; g < GP; g++) {
        size_t o = ((size_t)b * GP + g) * EE + t;
        h[o] = 0.0f; hb[o] = 0;
    }
}

// --------- QKV GEMM (A-in-regs): 128 rows/block, 8 waves, B streamed
// through 2x32KB LDS dbuf with counted vmcnt. ---------
__global__ __launch_bounds__(512) void qkv_gemm(
    const u16* __restrict__ hb, const u16* __restrict__ wqkvT,
    u16* __restrict__ qb, u16* __restrict__ kb, u16* __restrict__ vt)
{
    __shared__ __align__(16) u16 sB[2][16384];   // 2 x 32 KB (64n x 256k tile)
    int tid = threadIdx.x, lane = tid & 63, w = tid >> 6;   // w = 0..7
    int lr = lane & 15, q = lane >> 4, lk = q * 8;
    int brow = blockIdx.x * 128;

    const u16* abase = hb + ((size_t)(brow + w * 16 + lr)) * 256;
    bf16x8 af[8];
    #pragma unroll
    for (int k8 = 0; k8 < 8; k8++) af[k8] = *(const bf16x8*)(abase + k8 * 32 + lk);

    int rowG0 = brow + w * 16 + q * 4;
    int b0 = rowG0 / GP, g0 = rowG0 - b0 * GP;

    #pragma unroll
    for (int r = 0; r < 4; r++)
        stage_swz(wqkvT, 256, r * 64, sB[0] + r * 4096, 8, w, 8, lane);

    for (int nt = 0; nt < 12; nt++) {
        int cur = nt & 1;
        if (nt < 11) {
            #pragma unroll
            for (int r = 0; r < 4; r++)
                stage_swz(wqkvT + (size_t)(nt + 1) * 64 * 256, 256, r * 64,
                          sB[cur ^ 1] + r * 4096, 8, w, 8, lane);
            asm volatile("s_waitcnt vmcnt(4)" ::: "memory");
        } else {
            asm volatile("s_waitcnt vmcnt(0)" ::: "memory");
        }
        __builtin_amdgcn_s_barrier();

        f32x4 acc[4];
        #pragma unroll
        for (int n = 0; n < 4; n++) acc[n] = {0.0f, 0.0f, 0.0f, 0.0f};
        #pragma unroll
        for (int k8 = 0; k8 < 8; k8++) {
            bf16x8 a = af[k8];
            #pragma unroll
            for (int n = 0; n < 4; n++) {
                bf16x8 bb = lds_frag(sB[cur] + (k8 >> 1) * 4096, n * 16 + lr, k8 & 1, q);
                acc[n] = MFMA(a, bb, acc[n]);
            }
        }

        if (nt < 8) {
            u16* dst = (nt < 4) ? qb : kb;
            int cOff = (nt & 3) * 64;
            #pragma unroll
            for (int n = 0; n < 4; n++) {
                int col = cOff + n * 16 + lr;
                #pragma unroll
                for (int j = 0; j < 4; j++)
                    dst[(size_t)(rowG0 + j) * 256 + col] = f2bf(acc[n][j]);
            }
        } else {
            #pragma unroll
            for (int n = 0; n < 4; n++) {
                int e = (nt - 8) * 64 + n * 16 + lr;
                ushort4 u4;
                u4.x = f2bf(acc[n][0]);
                u4.y = f2bf(acc[n][1]);
                u4.z = f2bf(acc[n][2]);
                u4.w = f2bf(acc[n][3]);
                *(ushort4*)(vt + ((size_t)(b0 * EE + e)) * GP + g0) = u4;
            }
        }
        __builtin_amdgcn_sched_barrier(0);
        __builtin_amdgcn_s_barrier();
    }
}

// --------- FF1 GEMM (A-in-regs): 128 rows/block, 8 waves, 8 N-tiles of 64,
//           epilogue bias+relu -> hidb bf16 ---------
__global__ __launch_bounds__(512) void ff1_gemm(
    const u16* __restrict__ hb, const u16* __restrict__ w1T,
    const float* __restrict__ bf1, u16* __restrict__ hidb)
{
    __shared__ __align__(16) u16 sB[2][16384];
    int tid = threadIdx.x, lane = tid & 63, w = tid >> 6;
    int lr = lane & 15, q = lane >> 4, lk = q * 8;
    int brow = blockIdx.x * 128;

    const u16* abase = hb + ((size_t)(brow + w * 16 + lr)) * 256;
    bf16x8 af[8];
    #pragma unroll
    for (int k8 = 0; k8 < 8; k8++) af[k8] = *(const bf16x8*)(abase + k8 * 32 + lk);

    int rowG0 = brow + w * 16 + q * 4;

    #pragma unroll
    for (int r = 0; r < 4; r++)
        stage_swz(w1T, 256, r * 64, sB[0] + r * 4096, 8, w, 8, lane);

    for (int nt = 0; nt < 8; nt++) {
        int cur = nt & 1;
        if (nt < 7) {
            #pragma unroll
            for (int r = 0; r < 4; r++)
                stage_swz(w1T + (size_t)(nt + 1) * 64 * 256, 256, r * 64,
                          sB[cur ^ 1] + r * 4096, 8, w, 8, lane);
            asm volatile("s_waitcnt vmcnt(4)" ::: "memory");
        } else {
            asm volatile("s_waitcnt vmcnt(0)" ::: "memory");
        }
        __builtin_amdgcn_s_barrier();

        f32x4 acc[4];
        #pragma unroll
        for (int n = 0; n < 4; n++) acc[n] = {0.0f, 0.0f, 0.0f, 0.0f};
        #pragma unroll
        for (int k8 = 0; k8 < 8; k8++) {
            bf16x8 a = af[k8];
            #pragma unroll
            for (int n = 0; n < 4; n++) {
                bf16x8 bb = lds_frag(sB[cur] + (k8 >> 1) * 4096, n * 16 + lr, k8 & 1, q);
                acc[n] = MFMA(a, bb, acc[n]);
            }
        }

        #pragma unroll
        for (int n = 0; n < 4; n++) {
            int col = nt * 64 + n * 16 + lr;
            float bias = bf1[col];
            #pragma unroll
            for (int j = 0; j < 4; j++) {
                float v = acc[n][j] + bias;
                hidb[(size_t)(rowG0 + j) * 512 + col] = f2bf(fmaxf(v, 0.0f));
            }
        }
        __builtin_amdgcn_sched_barrier(0);
        __builtin_amdgcn_s_barrier();
    }
}

// ---- GEMM + residual + LayerNorm: BM=64, BN=256(full row), 8 waves,
//      dbuf counted-vmcnt staging. STR = K = A-stride = B-stride. ----
template<int KSTEPS, int STR, bool HASB>
__global__ __launch_bounds__(512) void gemmln_kernel(
    const u16* __restrict__ A, const u16* __restrict__ Bw,
    const float* __restrict__ bias, float* __restrict__ h, u16* __restrict__ hb)
{
    __shared__ __align__(16) u16 sA[2][64 * 64];    // 2 x 8 KB
    __shared__ __align__(16) u16 sB[2][256 * 64];   // 2 x 32 KB
    int tid = threadIdx.x, lane = tid & 63, w = tid >> 6;
    int wm = w >> 2, wn = w & 3;
    int lr = lane & 15, q = lane >> 4;
    int brow = blockIdx.x * 64;

    f32x4 acc[2][4];
    #pragma unroll
    for (int i = 0; i < 2; i++)
        #pragma unroll
        for (int j = 0; j < 4; j++) acc[i][j] = {0.0f, 0.0f, 0.0f, 0.0f};

    stage_swz(A + (size_t)brow * STR, STR, 0, sA[0], 8, w, 8, lane);
    stage_swz(Bw, STR, 0, sB[0], 32, w, 8, lane);

    for (int ks = 0; ks < KSTEPS; ks++) {
        int cur = ks & 1;
        if (ks + 1 < KSTEPS) {
            stage_swz(A + (size_t)brow * STR, STR, (ks + 1) * 64, sA[cur ^ 1], 8, w, 8, lane);
            stage_swz(Bw, STR, (ks + 1) * 64, sB[cur ^ 1], 32, w, 8, lane);
            asm volatile("s_waitcnt vmcnt(5)" ::: "memory");
        } else {
            asm volatile("s_waitcnt vmcnt(0)" ::: "memory");
        }
        __builtin_amdgcn_s_barrier();
        #pragma unroll
        for (int kk = 0; kk < 2; kk++) {
            bf16x8 a[2], b[4];
            #pragma unroll
            for (int i = 0; i < 2; i++)
                a[i] = lds_frag(sA[cur], wm * 32 + i * 16 + lr, kk, q);
            #pragma unroll
            for (int n = 0; n < 4; n++)
                b[n] = lds_frag(sB[cur], wn * 64 + n * 16 + lr, kk, q);
            #pragma unroll
            for (int mi = 0; mi < 2; mi++)
                #pragma unroll
                for (int ni = 0; ni < 4; ni++)
                    acc[mi][ni] = MFMA(a[mi], b[ni], acc[mi][ni]);
        }
        __builtin_amdgcn_sched_barrier(0);
        __builtin_amdgcn_s_barrier();
    }

    __syncthreads();
    float* sPart = (float*)sA;           // [4 wn][64 row][2] = 2 KB

    #pragma unroll
    for (int ni = 0; ni < 4; ni++) {
        int col = wn * 64 + ni * 16 + lr;
        float bv = HASB ? bias[col] : 0.0f;
        #pragma unroll
        for (int mi = 0; mi < 2; mi++)
            #pragma unroll
            for (int j = 0; j < 4; j++) {
                int rowG = brow + wm * 32 + mi * 16 + q * 4 + j;
                acc[mi][ni][j] += bv + h[(size_t)rowG * 256 + col];
            }
    }
    #pragma unroll
    for (int mi = 0; mi < 2; mi++)
        #pragma unroll
        for (int j = 0; j < 4; j++) {
            float s1 = 0.0f, s2 = 0.0f;
            #pragma unroll
            for (int ni = 0; ni < 4; ni++) {
                float v = acc[mi][ni][j];
                s1 += v; s2 += v * v;
            }
            s1 += __shfl_xor(s1, 1); s2 += __shfl_xor(s2, 1);
            s1 += __shfl_xor(s1, 2); s2 += __shfl_xor(s2, 2);
            s1 += __shfl_xor(s1, 4); s2 += __shfl_xor(s2, 4);
            s1 += __shfl_xor(s1, 8); s2 += __shfl_xor(s2, 8);
            if (lr == 0) {
                int lrow = wm * 32 + mi * 16 + q * 4 + j;
                sPart[(wn * 64 + lrow) * 2 + 0] = s1;
                sPart[(wn * 64 + lrow) * 2 + 1] = s2;
            }
        }
    __syncthreads();

    #pragma unroll
    for (int mi = 0; mi < 2; mi++)
        #pragma unroll
        for (int j = 0; j < 4; j++) {
            int lrow = wm * 32 + mi * 16 + q * 4 + j;
            float s1 = sPart[lrow * 2] + sPart[(64 + lrow) * 2] +
                       sPart[(128 + lrow) * 2] + sPart[(192 + lrow) * 2];
            float s2 = sPart[lrow * 2 + 1] + sPart[(64 + lrow) * 2 + 1] +
                       sPart[(128 + lrow) * 2 + 1] + sPart[(192 + lrow) * 2 + 1];
            float mean = s1 * (1.0f / 256.0f);
            float var  = s2 * (1.0f / 256.0f) - mean * mean;
            float rstd = rsqrtf(var + 1e-5f);
            int rowG = brow + lrow;
            #pragma unroll
            for (int ni = 0; ni < 4; ni++) {
                int col = wn * 64 + ni * 16 + lr;
                float v = (acc[mi][ni][j] - mean) * rstd;
                size_t o = (size_t)rowG * 256 + col;
                h[o] = v; hb[o] = f2bf(v);
            }
        }
}

// ------- attention core (flash-LDS, 2 blocks/CU) with L2-warm prefetch:
// kb/vt were written by qkv from OTHER XCDs -> first touch here costs
// cross-XCD/HBM latency on every staging phase. Prologue bulk-prefetches
// the batch's K (160KB) + V (160KB) into the local XCD L2 via 40 coalesced
// 16B reg loads/thread (asm-sunk), drained once before staging. All
// subsequent counted-vmcnt phases then hit warm L2.
__global__ __launch_bounds__(512) void attn_core(
    const u16* __restrict__ qb, const u16* __restrict__ kb,
    const u16* __restrict__ vt, const float* __restrict__ obs,
    u16* __restrict__ aob)
{
    __shared__ __align__(16) u16 sKV[2][16384];   // 64 KB: K tiles, then V tiles
    __shared__ __align__(16) u16 sPt[64 * 72];    // 9 KB: one 64-key P tile
    __shared__ float sBias[320];
    __shared__ float sPm[2][64], sPs[2][64];

    int id = blockIdx.x;                 // 1280 blocks
    int xcd = id & 7, jj = id >> 3;      // jj in [0,160)
    int tile = jj % 5, bgrp = jj / 5;    // bgrp in [0,32)
    int b = xcd + 8 * bgrp;              // bijective batch
    int t0 = tile * 64;

    int tid = threadIdx.x, w = tid >> 6, lane = tid & 63;
    int wm = w >> 1, wn = w & 1;         // row-quarter (16 rows), j/e-half
    int lr = lane & 15, q = lane >> 4, lk = q * 8;

    // ---- L2-warm prefetch: 20+20 coalesced 16B loads/thread, asm-sunk ----
    {
        const f32x4* kpre = (const f32x4*)(kb + (size_t)b * GP * 256);
        const f32x4* vpre = (const f32x4*)(vt + (size_t)b * EE * GP);
        #pragma unroll
        for (int i = 0; i < 20; i++) {
            f32x4 x = kpre[tid + i * 512];
            asm volatile("" :: "v"(x));
            f32x4 y = vpre[tid + i * 512];
            asm volatile("" :: "v"(y));
        }
    }

    if (tid < 320) {
        float msk = (tid < GG) ? obs[((size_t)b * GG + tid) * 9 + 8] : 0.0f;
        sBias[tid] = (1.0f - msk) * -1e9f;
    }

    const u16* qbase = qb + ((size_t)(b * GP + t0 + wm * 16 + lr)) * 256;
    bf16x8 af[8];
    #pragma unroll
    for (int k8 = 0; k8 < 8; k8++) af[k8] = *(const bf16x8*)(qbase + k8 * 32 + lk);

    const u16* vbase = vt + (size_t)b * EE * GP;

    // drain prefetch (+Q/bias) before staging so vmcnt accounting is exact;
    // bulk HBM transfer overlaps the co-resident block's compute
    asm volatile("s_waitcnt vmcnt(0)" ::: "memory");

    #pragma unroll
    for (int r = 0; r < 4; r++)
        stage_swz(kb + ((size_t)b * GP) * 256, 256, r * 64, sKV[0] + r * 4096, 8, w, 8, lane);

    f32x4 sacc[10];
    #pragma unroll
    for (int s = 0; s < 10; s++) sacc[s] = {0.0f, 0.0f, 0.0f, 0.0f};

    #pragma unroll
    for (int t = 0; t < 5; t++) {
        if (t < 4) {
            #pragma unroll
            for (int r = 0; r < 4; r++)
                stage_swz(kb + ((size_t)(b * GP + (t + 1) * 64)) * 256, 256, r * 64,
                          sKV[(t + 1) & 1] + r * 4096, 8, w, 8, lane);
            asm volatile("s_waitcnt vmcnt(4)" ::: "memory");
        } else {
            asm volatile("s_waitcnt vmcnt(0)" ::: "memory");
        }
        __builtin_amdgcn_s_barrier();
        const u16* kbuf = sKV[t & 1];
        #pragma unroll
        for (int ks = 0; ks < 4; ks++)
            #pragma unroll
            for (int kk = 0; kk < 2; kk++) {
                bf16x8 a = af[ks * 2 + kk];
                #pragma unroll
                for (int l = 0; l < 2; l++) {
                    int jl = (wn * 2 + l) * 16 + lr;
                    bf16x8 bb = lds_frag(kbuf + ks * 4096, jl, kk, q);
                    sacc[t * 2 + l] = MFMA(a, bb, sacc[t * 2 + l]);
                }
            }
        __builtin_amdgcn_s_barrier();
    }

    #pragma unroll
    for (int s = 0; s < 10; s++) {
        int j = (s >> 1) * 64 + (wn * 2 + (s & 1)) * 16 + lr;
        float bia = sBias[j];
        #pragma unroll
        for (int r = 0; r < 4; r++) sacc[s][r] = sacc[s][r] * 0.0625f + bia;
    }
    #pragma unroll
    for (int r = 0; r < 4; r++) {
        float mx = -1e30f;
        #pragma unroll
        for (int s = 0; s < 10; s++) mx = fmaxf(mx, sacc[s][r]);
        mx = fmaxf(mx, __shfl_xor(mx, 1));
        mx = fmaxf(mx, __shfl_xor(mx, 2));
        mx = fmaxf(mx, __shfl_xor(mx, 4));
        mx = fmaxf(mx, __shfl_xor(mx, 8));
        if (lr == 0) sPm[wn][wm * 16 + q * 4 + r] = mx;
    }
    __syncthreads();   // no vmem outstanding here (K loop drained to 0)

    stage_swz(vbase, GP, 0 * 64, sKV[0], 32, w, 8, lane);

    #pragma unroll
    for (int r = 0; r < 4; r++) {
        int row = wm * 16 + q * 4 + r;
        float rm = fmaxf(sPm[0][row], sPm[1][row]);
        float ss = 0.0f;
        #pragma unroll
        for (int s = 0; s < 10; s++) {
            float e = __expf(sacc[s][r] - rm);
            sacc[s][r] = e;
            ss += e;
        }
        ss += __shfl_xor(ss, 1);
        ss += __shfl_xor(ss, 2);
        ss += __shfl_xor(ss, 4);
        ss += __shfl_xor(ss, 8);
        if (lr == 0) sPs[wn][row] = ss;
    }
    asm volatile("s_waitcnt lgkmcnt(0)" ::: "memory");
    __builtin_amdgcn_s_barrier();
    __builtin_amdgcn_sched_barrier(0);

    float invr[4];
    #pragma unroll
    for (int r = 0; r < 4; r++) {
        int row = wm * 16 + q * 4 + r;
        invr[r] = 1.0f / (sPs[0][row] + sPs[1][row]);
    }
    unsigned pk[10][2];
    #pragma unroll
    for (int s = 0; s < 10; s++) {
        pk[s][0] = (unsigned)f2bf(sacc[s][0] * invr[0]) |
                   ((unsigned)f2bf(sacc[s][1] * invr[1]) << 16);
        pk[s][1] = (unsigned)f2bf(sacc[s][2] * invr[2]) |
                   ((unsigned)f2bf(sacc[s][3] * invr[3]) << 16);
    }

    f32x4 oacc[8];
    #pragma unroll
    for (int n = 0; n < 8; n++) oacc[n] = {0.0f, 0.0f, 0.0f, 0.0f};

    #pragma unroll
    for (int c = 0; c < 5; c++) {
        if (c < 4) {
            stage_swz(vbase, GP, (c + 1) * 64, sKV[(c + 1) & 1], 32, w, 8, lane);
            asm volatile("s_waitcnt vmcnt(4)" ::: "memory");
        } else {
            asm volatile("s_waitcnt vmcnt(0)" ::: "memory");
        }
        __builtin_amdgcn_s_barrier();
        #pragma unroll
        for (int sl = 0; sl < 2; sl++) {
            int jl = (wn * 2 + sl) * 16 + lr;
            #pragma unroll
            for (int r = 0; r < 4; r++) {
                int row = wm * 16 + q * 4 + r;
                unsigned v = pk[c * 2 + sl][r >> 1];
                sPt[row * 72 + jl] = (u16)((r & 1) ? (v >> 16) : (v & 0xffffu));
            }
        }
        asm volatile("s_waitcnt lgkmcnt(0)" ::: "memory");
        __builtin_amdgcn_s_barrier();
        __builtin_amdgcn_sched_barrier(0);
        #pragma unroll
        for (int kk = 0; kk < 2; kk++) {
            bf16x8 a = *(const bf16x8*)(sPt + (wm * 16 + lr) * 72 + kk * 32 + lk);
            #pragma unroll
            for (int n = 0; n < 8; n++) {
                bf16x8 vv = lds_frag(sKV[c & 1], wn * 128 + n * 16 + lr, kk, q);
                oacc[n] = MFMA(a, vv, oacc[n]);
            }
        }
        __builtin_amdgcn_s_barrier();
    }

    #pragma unroll
    for (int n = 0; n < 8; n++) {
        int col = wn * 128 + n * 16 + lr;
        #pragma unroll
        for (int r = 0; r < 4; r++) {
            int row = wm * 16 + q * 4 + r;
            aob[((size_t)(b * GP + t0 + row)) * 256 + col] = f2bf(oacc[n][r]);
        }
    }
}

// ------------- head part 1 (wide): graph embed -> fc -> u[b] -------------
// 1024 threads: 16 g-stripes x 64 float4-cols. Serial chain 301 -> 19 iters.
__global__ __launch_bounds__(1024) void final1_kernel(
    const float* __restrict__ h, const float* __restrict__ obs,
    const float* __restrict__ w_fc, const float* __restrict__ w_pn,
    float* __restrict__ u)
{
    __shared__ float part[16][256];   // 16 KB
    __shared__ float vpart[16];
    __shared__ float ges[EE];
    __shared__ float fcs[EE];

    int b = blockIdx.x;
    int t = threadIdx.x;
    int c4 = (t & 63) * 4;
    int st = t >> 6;                  // 0..15

    float a0 = 0.0f, a1 = 0.0f, a2 = 0.0f, a3 = 0.0f, vl = 0.0f;
    for (int g = st; g < GG; g += 16) {
        float m = obs[((size_t)b * GG + g) * 9 + 8];
        float4 hv = *(const float4*)(h + ((size_t)b * GP + g) * EE + c4);
        a0 += hv.x * m; a1 += hv.y * m; a2 += hv.z * m; a3 += hv.w * m;
        vl += m;
    }
    part[st][c4 + 0] = a0; part[st][c4 + 1] = a1;
    part[st][c4 + 2] = a2; part[st][c4 + 3] = a3;
    if ((t & 63) == 0) vpart[st] = vl;
    __syncthreads();

    if (t < 256) {
        float s = 0.0f;
        #pragma unroll
        for (int i = 0; i < 16; i++) s += part[i][t];
        float vsum = 0.0f;
        #pragma unroll
        for (int i = 0; i < 16; i++) vsum += vpart[i];
        ges[t] = s / vsum;
    }
    __syncthreads();

    {
        int col = t & 255, kq = t >> 8;
        float fcp = 0.0f;
        for (int i = 0; i < 64; i++) {
            int kk = kq * 64 + i;
            fcp += ges[kk] * w_fc[kk * EE + col];
        }
        part[kq][col] = fcp;
    }
    __syncthreads();
    if (t < 256) fcs[t] = part[0][t] + part[1][t] + part[2][t] + part[3][t];
    __syncthreads();

    {
        int e = t & 255, kq = t >> 8;
        const float4* wp = reinterpret_cast<const float4*>(w_pn + (size_t)e * 3 * EE + kq * 64);
        float ua = 0.0f;
        #pragma unroll
        for (int i = 0; i < 16; i++) {
            float4 w = wp[i];
            int base = kq * 64 + i * 4;
            ua += w.x * fcs[base] + w.y * fcs[base + 1] +
                  w.z * fcs[base + 2] + w.w * fcs[base + 3];
        }
        part[kq][e] = ua;
    }
    __syncthreads();
    if (t < 256)
        u[(size_t)b * EE + t] = part[0][t] + part[1][t] + part[2][t] + part[3][t];
}

// ------------- head part 2: compat -> tanh clip -> masked softmax -------------
__global__ __launch_bounds__(128) void final2_kernel(
    const float* __restrict__ h, const float* __restrict__ obs,
    const float* __restrict__ u, float* __restrict__ out)
{
    int b = blockIdx.x;
    int t = threadIdx.x;
    __shared__ float us[EE];
    __shared__ float red[8];
    us[t]       = u[(size_t)b * EE + t];
    us[t + 128] = u[(size_t)b * EE + t + 128];
    __syncthreads();

    float logit = -INFINITY;
    float m = 0.0f;
    if (t < LHN) {
        int g = IHN + t;
        m = obs[((size_t)b * GG + g) * 9 + 8];
        const float4* hr = reinterpret_cast<const float4*>(h + ((size_t)b * GP + g) * EE);
        float c = 0.0f;
        for (int kk = 0; kk < EE / 4; kk++) {
            float4 hv = hr[kk];
            c += hv.x * us[kk * 4] + hv.y * us[kk * 4 + 1] +
                 hv.z * us[kk * 4 + 2] + hv.w * us[kk * 4 + 3];
        }
        c *= m;
        c *= 0.0625f;
        logit = tanhf(c) * 10.0f;
    }
    float bm = blockReduceMax(logit, red);
    float e  = (t < LHN) ? __expf(logit - bm) : 0.0f;
    float bs = blockReduceSum(e, red);
    float p  = e / bs;
    float masked = (t < LHN) ? (p * m + 1e-20f) : 0.0f;
    float bs2 = blockReduceSum(masked, red);
    if (t < LHN) out[(size_t)b * LHN + t] = masked / bs2;
}

extern "C" void kernel_launch(void* const* d_in, const int* in_sizes, int n_in,
                              void* d_out, int out_size, void* d_ws, size_t ws_size,
                              hipStream_t stream) {
    const float* obs   = (const float*)d_in[0];
    const float* wi1   = (const float*)d_in[1];
    const float* bi1   = (const float*)d_in[2];
    const float* wi2   = (const float*)d_in[3];
    const float* bi2   = (const float*)d_in[4];
    const float* wl1   = (const float*)d_in[5];
    const float* bl1   = (const float*)d_in[6];
    const float* wl2   = (const float*)d_in[7];
    const float* bl2   = (const float*)d_in[8];
    const float* wn1   = (const float*)d_in[9];
    const float* bn1   = (const float*)d_in[10];
    const float* wn2   = (const float*)d_in[11];
    const float* bn2   = (const float*)d_in[12];
    const float* e_wq  = (const float*)d_in[13];
    const float* e_wk  = (const float*)d_in[14];
    const float* e_wv  = (const float*)d_in[15];
    const float* e_wo  = (const float*)d_in[16];
    const float* e_wf1 = (const float*)d_in[17];
    const float* e_bf1 = (const float*)d_in[18];
    const float* e_wf2 = (const float*)d_in[19];
    const float* e_bf2 = (const float*)d_in[20];
    const float* w_pn  = (const float*)d_in[21];
    const float* w_fc  = (const float*)d_in[22];
    float* outp = (float*)d_out;

    // ---- compact workspace layout: 254,017,536 B total ----
    char* wsc = (char*)d_ws;
    float* h    = (float*)wsc;
    u16*   hb   = (u16*)(wsc + 83886080);
    u16*   qaob = (u16*)(wsc + 125829120);   // qb, later aob
    u16*   kb   = (u16*)(wsc + 167772160);
    u16*   vt   = (u16*)(wsc + 209715200);
    u16*   wT   = (u16*)(wsc + 251658240);
    float* ubuf = (float*)(wsc + 253755392);
    u16*   hidb = kb;  // overlays kb+vt (disjoint lifetime)

    prep_kernel<<<dim3(512, 12), 256, 0, stream>>>(e_wq, e_wk, e_wv, e_wo, e_wf1, e_wf2, wT);
    pad_kernel<<<BB, 256, 0, stream>>>(h, hb);
    embed_seg<ILN, IHN, 0><<<IHN * BB / 32, 256, 0, stream>>>(obs, wi1, bi1, wi2, bi2, h, hb);
    embed_seg<8, LHN, IHN><<<LHN * BB / 32, 256, 0, stream>>>(obs, wl1, bl1, wl2, bl2, h, hb);
    embed_seg<6, 1, IHN + LHN><<<BB / 32, 256, 0, stream>>>(obs, wn1, bn1, wn2, bn2, h, hb);

    const size_t WL = 524288;
    for (int l = 0; l < NL; l++) {
        u16* wqkvT = wT + l * WL;
        u16* woT   = wqkvT + 196608;
        u16* w1T   = wqkvT + 262144;
        u16* w2T   = wqkvT + 393216;
        const float* bf1 = e_bf1 + (size_t)l * FFH;
        const float* bf2 = e_bf2 + (size_t)l * EE;

        qkv_gemm<<<MT / 128, 512, 0, stream>>>(hb, wqkvT, qaob, kb, vt);
        attn_core<<<1280, 512, 0, stream>>>(qaob, kb, vt, obs, qaob);
        gemmln_kernel<4, 256, false><<<MT / 64, 512, 0, stream>>>(qaob, woT, nullptr, h, hb);
        ff1_gemm<<<MT / 128, 512, 0, stream>>>(hb, w1T, bf1, hidb);
        gemmln_kernel<8, 512, true><<<MT / 64, 512, 0, stream>>>(hidb, w2T, bf2, h, hb);
    }
    final1_kernel<<<BB, 1024, 0, stream>>>(h, obs, w_fc, w_pn, ubuf);
    final2_kernel<<<BB, 128, 0, stream>>>(h, obs, ubuf, outp);
}

// Round 18
// 587.168 us; speedup vs baseline: 1.1044x; 1.1044x over previous
//
#include <hip/hip_runtime.h>
#include <math.h>

static constexpr int BB   = 256;   // batch
static constexpr int IHN  = 200;   // internal tokens
static constexpr int ILN  = 6;    // internal feature dim
static constexpr int LHN  = 100;   // leaf tokens
static constexpr int EE   = 256;   // embed dim
static constexpr int FFH  = 512;   // ff hidden
static constexpr int NL   = 2;     // layers
static constexpr int GG   = 301;   // real tokens
static constexpr int GP   = 320;   // padded tokens (10 x 32)
static constexpr int MT   = BB * GP;  // 81920 total token rows

typedef unsigned short u16;
typedef short bf16x8 __attribute__((ext_vector_type(8)));
typedef float f32x4 __attribute__((ext_vector_type(4)));

#define MFMA(a, b, c) __builtin_amdgcn_mfma_f32_16x16x32_bf16((a), (b), (c), 0, 0, 0)

__device__ __forceinline__ u16 f2bf(float f) {
    union { float f; unsigned u; } v; v.f = f;
    unsigned r = v.u + 0x7FFFu + ((v.u >> 16) & 1u);
    return (u16)(r >> 16);
}

// ---------------- wave/block reduction helpers (wave = 64) ----------------
__device__ __forceinline__ float waveReduceSum(float v) {
    for (int o = 32; o > 0; o >>= 1) v += __shfl_down(v, o, 64);
    return v;
}
__device__ __forceinline__ float waveReduceMax(float v) {
    for (int o = 32; o > 0; o >>= 1) v = fmaxf(v, __shfl_down(v, o, 64));
    return v;
}
__device__ __forceinline__ float blockReduceSum(float v, float* red) {
    int lane = threadIdx.x & 63;
    int w    = threadIdx.x >> 6;
    int nw   = (blockDim.x + 63) >> 6;
    v = waveReduceSum(v);
    if (lane == 0) red[w] = v;
    __syncthreads();
    if (threadIdx.x < 64) {
        float x = (lane < nw) ? red[lane] : 0.0f;
        x = waveReduceSum(x);
        if (lane == 0) red[0] = x;
    }
    __syncthreads();
    float r = red[0];
    __syncthreads();
    return r;
}
__device__ __forceinline__ float blockReduceMax(float v, float* red) {
    int lane = threadIdx.x & 63;
    int w    = threadIdx.x >> 6;
    int nw   = (blockDim.x + 63) >> 6;
    v = waveReduceMax(v);
    if (lane == 0) red[w] = v;
    __syncthreads();
    if (threadIdx.x < 64) {
        float x = (lane < nw) ? red[lane] : -INFINITY;
        x = waveReduceMax(x);
        if (lane == 0) red[0] = x;
    }
    __syncthreads();
    float r = red[0];
    __syncthreads();
    return r;
}

// --------- staging: global -> LDS tile [rows][64] bf16, XOR-swizzled ---------
__device__ __forceinline__ void stage_swz(const u16* src, int strideShorts, int k0,
                                          u16* ldsTile, int nChunks, int wave,
                                          int nWaves, int lane)
{
    for (int c = wave; c < nChunks; c += nWaves) {
        int o = c * 1024 + lane * 16;
        int row = o >> 7;
        int cb = (o & 127) ^ ((row & 7) << 4);
        const u16* g = src + (size_t)row * strideShorts + k0 + (cb >> 1);
        __builtin_amdgcn_global_load_lds(
            (const __attribute__((address_space(1))) unsigned int*)g,
            (__attribute__((address_space(3))) unsigned int*)((char*)ldsTile + c * 1024),
            16, 0, 0);
    }
}

__device__ __forceinline__ bf16x8 lds_frag(const u16* tile, int row, int kk, int q)
{
    int cb = (kk * 64 + q * 16) ^ ((row & 7) << 4);
    return *(const bf16x8*)((const char*)tile + row * 128 + cb);
}

// ------------- prep: transpose encoder weights to bf16 [N][K] -------------
__global__ __launch_bounds__(256) void prep_kernel(
    const float* __restrict__ wq, const float* __restrict__ wk,
    const float* __restrict__ wv, const float* __restrict__ wo,
    const float* __restrict__ wf1, const float* __restrict__ wf2,
    u16* __restrict__ wT)
{
    int l = blockIdx.y / 6, m = blockIdx.y % 6;
    int idx = blockIdx.x * 256 + threadIdx.x;
    u16* dst = wT + (size_t)l * 524288;
    if (m < 4) {
        if (idx >= EE * EE) return;
        const float* src = (m == 0 ? wq : m == 1 ? wk : m == 2 ? wv : wo) + (size_t)l * EE * EE;
        int r = idx >> 8, c = idx & 255;
        dst[m * 65536 + idx] = f2bf(src[(size_t)c * EE + r]);
    } else if (m == 4) {
        if (idx >= FFH * EE) return;
        const float* src = wf1 + (size_t)l * EE * FFH;
        int r = idx >> 8, c = idx & 255;
        dst[262144 + idx] = f2bf(src[(size_t)c * FFH + r]);
    } else {
        if (idx >= EE * FFH) return;
        const float* src = wf2 + (size_t)l * FFH * EE;
        int r = idx >> 9, c = idx & 511;
        dst[393216 + idx] = f2bf(src[(size_t)c * EE + r]);
    }
}

// ---------- embed (segment version): 32 tokens/block, w2 col in regs ----------
template<int IND, int SEG, int G0>
__global__ __launch_bounds__(256) void embed_seg(
    const float* __restrict__ obs,
    const float* __restrict__ w1, const float* __restrict__ b1,
    const float* __restrict__ w2, const float* __restrict__ b2,
    float* __restrict__ h, u16* __restrict__ hb)
{
    __shared__ float xs[32][9];
    __shared__ float hid[32][33];
    int t = threadIdx.x;
    int fi0 = blockIdx.x * 32;

    for (int p = t; p < 32 * 9; p += 256) {
        int tok = p / 9, f = p % 9;
        int fi = fi0 + tok;
        int b = fi / SEG, g = G0 + fi % SEG;
        xs[tok][f] = obs[((size_t)b * GG + g) * 9 + f];
    }
    __syncthreads();

    #pragma unroll
    for (int p = 0; p < 4; p++) {
        int idx = p * 256 + t;
        int tok = idx >> 5, hcol = idx & 31;
        float a = b1[hcol];
        #pragma unroll
        for (int i = 0; i < IND; i++) a += xs[tok][i] * w1[i * 32 + hcol];
        hid[tok][hcol] = (a > 0.0f) ? a : 0.01f * a;
    }
    __syncthreads();

    float w2c[32];
    #pragma unroll
    for (int j = 0; j < 32; j++) w2c[j] = w2[j * EE + t];
    float bb = b2[t];
    for (int tok = 0; tok < 32; tok++) {
        int fi = fi0 + tok;
        int b = fi / SEG, g = G0 + fi % SEG;
        float a = bb;
        #pragma unroll
        for (int j = 0; j < 32; j++) a += hid[tok][j] * w2c[j];
        size_t o = ((size_t)b * GP + g) * EE + t;
        h[o] = a; hb[o] = f2bf(a);
    }
}

// zero the pad rows g in [GG, GP)
__global__ __launch_bounds__(256) void pad_kernel(float* __restrict__ h, u16* __restrict__ hb)
{
    int b = blockIdx.x, t = threadIdx.x;
    for (int g = GG; g < GP; g++) {
        size_t o = ((size_t)b * GP + g) * EE + t;
        h[o] = 0.0f; hb[o] = 0;
    }
}

// --------- QKV GEMM (A-in-regs): 128 rows/block, 8 waves, B streamed
// through 2x32KB LDS dbuf with counted vmcnt. ---------
__global__ __launch_bounds__(512) void qkv_gemm(
    const u16* __restrict__ hb, const u16* __restrict__ wqkvT,
    u16* __restrict__ qb, u16* __restrict__ kb, u16* __restrict__ vt)
{
    __shared__ __align__(16) u16 sB[2][16384];   // 2 x 32 KB (64n x 256k tile)
    int tid = threadIdx.x, lane = tid & 63, w = tid >> 6;   // w = 0..7
    int lr = lane & 15, q = lane >> 4, lk = q * 8;
    int brow = blockIdx.x * 128;

    const u16* abase = hb + ((size_t)(brow + w * 16 + lr)) * 256;
    bf16x8 af[8];
    #pragma unroll
    for (int k8 = 0; k8 < 8; k8++) af[k8] = *(const bf16x8*)(abase + k8 * 32 + lk);

    int rowG0 = brow + w * 16 + q * 4;
    int b0 = rowG0 / GP, g0 = rowG0 - b0 * GP;

    #pragma unroll
    for (int r = 0; r < 4; r++)
        stage_swz(wqkvT, 256, r * 64, sB[0] + r * 4096, 8, w, 8, lane);

    for (int nt = 0; nt < 12; nt++) {
        int cur = nt & 1;
        if (nt < 11) {
            #pragma unroll
            for (int r = 0; r < 4; r++)
                stage_swz(wqkvT + (size_t)(nt + 1) * 64 * 256, 256, r * 64,
                          sB[cur ^ 1] + r * 4096, 8, w, 8, lane);
            asm volatile("s_waitcnt vmcnt(4)" ::: "memory");
        } else {
            asm volatile("s_waitcnt vmcnt(0)" ::: "memory");
        }
        __builtin_amdgcn_s_barrier();

        f32x4 acc[4];
        #pragma unroll
        for (int n = 0; n < 4; n++) acc[n] = {0.0f, 0.0f, 0.0f, 0.0f};
        #pragma unroll
        for (int k8 = 0; k8 < 8; k8++) {
            bf16x8 a = af[k8];
            #pragma unroll
            for (int n = 0; n < 4; n++) {
                bf16x8 bb = lds_frag(sB[cur] + (k8 >> 1) * 4096, n * 16 + lr, k8 & 1, q);
                acc[n] = MFMA(a, bb, acc[n]);
            }
        }

        if (nt < 8) {
            u16* dst = (nt < 4) ? qb : kb;
            int cOff = (nt & 3) * 64;
            #pragma unroll
            for (int n = 0; n < 4; n++) {
                int col = cOff + n * 16 + lr;
                #pragma unroll
                for (int j = 0; j < 4; j++)
                    dst[(size_t)(rowG0 + j) * 256 + col] = f2bf(acc[n][j]);
            }
        } else {
            #pragma unroll
            for (int n = 0; n < 4; n++) {
                int e = (nt - 8) * 64 + n * 16 + lr;
                ushort4 u4;
                u4.x = f2bf(acc[n][0]);
                u4.y = f2bf(acc[n][1]);
                u4.z = f2bf(acc[n][2]);
                u4.w = f2bf(acc[n][3]);
                *(ushort4*)(vt + ((size_t)(b0 * EE + e)) * GP + g0) = u4;
            }
        }
        __builtin_amdgcn_sched_barrier(0);
        __builtin_amdgcn_s_barrier();
    }
}

// --------- FF1 GEMM (A-in-regs): 128 rows/block, 8 waves, 8 N-tiles of 64,
//           epilogue bias+relu -> hidb bf16 ---------
__global__ __launch_bounds__(512) void ff1_gemm(
    const u16* __restrict__ hb, const u16* __restrict__ w1T,
    const float* __restrict__ bf1, u16* __restrict__ hidb)
{
    __shared__ __align__(16) u16 sB[2][16384];
    int tid = threadIdx.x, lane = tid & 63, w = tid >> 6;
    int lr = lane & 15, q = lane >> 4, lk = q * 8;
    int brow = blockIdx.x * 128;

    const u16* abase = hb + ((size_t)(brow + w * 16 + lr)) * 256;
    bf16x8 af[8];
    #pragma unroll
    for (int k8 = 0; k8 < 8; k8++) af[k8] = *(const bf16x8*)(abase + k8 * 32 + lk);

    int rowG0 = brow + w * 16 + q * 4;

    #pragma unroll
    for (int r = 0; r < 4; r++)
        stage_swz(w1T, 256, r * 64, sB[0] + r * 4096, 8, w, 8, lane);

    for (int nt = 0; nt < 8; nt++) {
        int cur = nt & 1;
        if (nt < 7) {
            #pragma unroll
            for (int r = 0; r < 4; r++)
                stage_swz(w1T + (size_t)(nt + 1) * 64 * 256, 256, r * 64,
                          sB[cur ^ 1] + r * 4096, 8, w, 8, lane);
            asm volatile("s_waitcnt vmcnt(4)" ::: "memory");
        } else {
            asm volatile("s_waitcnt vmcnt(0)" ::: "memory");
        }
        __builtin_amdgcn_s_barrier();

        f32x4 acc[4];
        #pragma unroll
        for (int n = 0; n < 4; n++) acc[n] = {0.0f, 0.0f, 0.0f, 0.0f};
        #pragma unroll
        for (int k8 = 0; k8 < 8; k8++) {
            bf16x8 a = af[k8];
            #pragma unroll
            for (int n = 0; n < 4; n++) {
                bf16x8 bb = lds_frag(sB[cur] + (k8 >> 1) * 4096, n * 16 + lr, k8 & 1, q);
                acc[n] = MFMA(a, bb, acc[n]);
            }
        }

        #pragma unroll
        for (int n = 0; n < 4; n++) {
            int col = nt * 64 + n * 16 + lr;
            float bias = bf1[col];
            #pragma unroll
            for (int j = 0; j < 4; j++) {
                float v = acc[n][j] + bias;
                hidb[(size_t)(rowG0 + j) * 512 + col] = f2bf(fmaxf(v, 0.0f));
            }
        }
        __builtin_amdgcn_sched_barrier(0);
        __builtin_amdgcn_s_barrier();
    }
}

// ---- GEMM + residual + LayerNorm: BM=64, BN=256(full row), 8 waves,
//      dbuf counted-vmcnt staging. STR = K = A-stride = B-stride. ----
template<int KSTEPS, int STR, bool HASB>
__global__ __launch_bounds__(512) void gemmln_kernel(
    const u16* __restrict__ A, const u16* __restrict__ Bw,
    const float* __restrict__ bias, float* __restrict__ h, u16* __restrict__ hb)
{
    __shared__ __align__(16) u16 sA[2][64 * 64];    // 2 x 8 KB
    __shared__ __align__(16) u16 sB[2][256 * 64];   // 2 x 32 KB
    int tid = threadIdx.x, lane = tid & 63, w = tid >> 6;
    int wm = w >> 2, wn = w & 3;
    int lr = lane & 15, q = lane >> 4;
    int brow = blockIdx.x * 64;

    f32x4 acc[2][4];
    #pragma unroll
    for (int i = 0; i < 2; i++)
        #pragma unroll
        for (int j = 0; j < 4; j++) acc[i][j] = {0.0f, 0.0f, 0.0f, 0.0f};

    stage_swz(A + (size_t)brow * STR, STR, 0, sA[0], 8, w, 8, lane);
    stage_swz(Bw, STR, 0, sB[0], 32, w, 8, lane);

    for (int ks = 0; ks < KSTEPS; ks++) {
        int cur = ks & 1;
        if (ks + 1 < KSTEPS) {
            stage_swz(A + (size_t)brow * STR, STR, (ks + 1) * 64, sA[cur ^ 1], 8, w, 8, lane);
            stage_swz(Bw, STR, (ks + 1) * 64, sB[cur ^ 1], 32, w, 8, lane);
            asm volatile("s_waitcnt vmcnt(5)" ::: "memory");
        } else {
            asm volatile("s_waitcnt vmcnt(0)" ::: "memory");
        }
        __builtin_amdgcn_s_barrier();
        #pragma unroll
        for (int kk = 0; kk < 2; kk++) {
            bf16x8 a[2], b[4];
            #pragma unroll
            for (int i = 0; i < 2; i++)
                a[i] = lds_frag(sA[cur], wm * 32 + i * 16 + lr, kk, q);
            #pragma unroll
            for (int n = 0; n < 4; n++)
                b[n] = lds_frag(sB[cur], wn * 64 + n * 16 + lr, kk, q);
            #pragma unroll
            for (int mi = 0; mi < 2; mi++)
                #pragma unroll
                for (int ni = 0; ni < 4; ni++)
                    acc[mi][ni] = MFMA(a[mi], b[ni], acc[mi][ni]);
        }
        __builtin_amdgcn_sched_barrier(0);
        __builtin_amdgcn_s_barrier();
    }

    __syncthreads();
    float* sPart = (float*)sA;           // [4 wn][64 row][2] = 2 KB

    #pragma unroll
    for (int ni = 0; ni < 4; ni++) {
        int col = wn * 64 + ni * 16 + lr;
        float bv = HASB ? bias[col] : 0.0f;
        #pragma unroll
        for (int mi = 0; mi < 2; mi++)
            #pragma unroll
            for (int j = 0; j < 4; j++) {
                int rowG = brow + wm * 32 + mi * 16 + q * 4 + j;
                acc[mi][ni][j] += bv + h[(size_t)rowG * 256 + col];
            }
    }
    #pragma unroll
    for (int mi = 0; mi < 2; mi++)
        #pragma unroll
        for (int j = 0; j < 4; j++) {
            float s1 = 0.0f, s2 = 0.0f;
            #pragma unroll
            for (int ni = 0; ni < 4; ni++) {
                float v = acc[mi][ni][j];
                s1 += v; s2 += v * v;
            }
            s1 += __shfl_xor(s1, 1); s2 += __shfl_xor(s2, 1);
            s1 += __shfl_xor(s1, 2); s2 += __shfl_xor(s2, 2);
            s1 += __shfl_xor(s1, 4); s2 += __shfl_xor(s2, 4);
            s1 += __shfl_xor(s1, 8); s2 += __shfl_xor(s2, 8);
            if (lr == 0) {
                int lrow = wm * 32 + mi * 16 + q * 4 + j;
                sPart[(wn * 64 + lrow) * 2 + 0] = s1;
                sPart[(wn * 64 + lrow) * 2 + 1] = s2;
            }
        }
    __syncthreads();

    #pragma unroll
    for (int mi = 0; mi < 2; mi++)
        #pragma unroll
        for (int j = 0; j < 4; j++) {
            int lrow = wm * 32 + mi * 16 + q * 4 + j;
            float s1 = sPart[lrow * 2] + sPart[(64 + lrow) * 2] +
                       sPart[(128 + lrow) * 2] + sPart[(192 + lrow) * 2];
            float s2 = sPart[lrow * 2 + 1] + sPart[(64 + lrow) * 2 + 1] +
                       sPart[(128 + lrow) * 2 + 1] + sPart[(192 + lrow) * 2 + 1];
            float mean = s1 * (1.0f / 256.0f);
            float var  = s2 * (1.0f / 256.0f) - mean * mean;
            float rstd = rsqrtf(var + 1e-5f);
            int rowG = brow + lrow;
            #pragma unroll
            for (int ni = 0; ni < 4; ni++) {
                int col = wn * 64 + ni * 16 + lr;
                float v = (acc[mi][ni][j] - mean) * rstd;
                size_t o = (size_t)rowG * 256 + col;
                h[o] = v; hb[o] = f2bf(v);
            }
        }
}

// ------- attention core (flash-LDS, 2 blocks/CU): K/V staged via
// global_load_lds with counted-vmcnt prefetch; two-pass softmax; P kept
// packed-bf16 in REGISTERS and written per-tile to a single 9 KB LDS tile
// (stride 72 -> 2-way banks). LDS total ~77 KB -> 2 blocks/CU.
// 64 q-rows/block, 512 thr (8 waves: wm row-quarter, wn j/e-half).
// aob may alias qb: Q read into regs at block start, aob written at end.
__global__ __launch_bounds__(512) void attn_core(
    const u16* __restrict__ qb, const u16* __restrict__ kb,
    const u16* __restrict__ vt, const float* __restrict__ obs,
    u16* __restrict__ aob)
{
    __shared__ __align__(16) u16 sKV[2][16384];   // 64 KB: K tiles, then V tiles
    __shared__ __align__(16) u16 sPt[64 * 72];    // 9 KB: one 64-key P tile
    __shared__ float sBias[320];
    __shared__ float sPm[2][64], sPs[2][64];

    int id = blockIdx.x;                 // 1280 blocks
    int xcd = id & 7, jj = id >> 3;      // jj in [0,160)
    int tile = jj % 5, bgrp = jj / 5;    // bgrp in [0,32)
    int b = xcd + 8 * bgrp;              // bijective batch
    int t0 = tile * 64;

    int tid = threadIdx.x, w = tid >> 6, lane = tid & 63;
    int wm = w >> 1, wn = w & 1;         // row-quarter (16 rows), j/e-half
    int lr = lane & 15, q = lane >> 4, lk = q * 8;

    if (tid < 320) {
        float msk = (tid < GG) ? obs[((size_t)b * GG + tid) * 9 + 8] : 0.0f;
        sBias[tid] = (1.0f - msk) * -1e9f;
    }

    const u16* qbase = qb + ((size_t)(b * GP + t0 + wm * 16 + lr)) * 256;
    bf16x8 af[8];
    #pragma unroll
    for (int k8 = 0; k8 < 8; k8++) af[k8] = *(const bf16x8*)(qbase + k8 * 32 + lk);

    const u16* vbase = vt + (size_t)b * EE * GP;

    #pragma unroll
    for (int r = 0; r < 4; r++)
        stage_swz(kb + ((size_t)b * GP) * 256, 256, r * 64, sKV[0] + r * 4096, 8, w, 8, lane);

    f32x4 sacc[10];
    #pragma unroll
    for (int s = 0; s < 10; s++) sacc[s] = {0.0f, 0.0f, 0.0f, 0.0f};

    #pragma unroll
    for (int t = 0; t < 5; t++) {
        if (t < 4) {
            #pragma unroll
            for (int r = 0; r < 4; r++)
                stage_swz(kb + ((size_t)(b * GP + (t + 1) * 64)) * 256, 256, r * 64,
                          sKV[(t + 1) & 1] + r * 4096, 8, w, 8, lane);
            asm volatile("s_waitcnt vmcnt(4)" ::: "memory");
        } else {
            asm volatile("s_waitcnt vmcnt(0)" ::: "memory");
        }
        __builtin_amdgcn_s_barrier();
        const u16* kbuf = sKV[t & 1];
        #pragma unroll
        for (int ks = 0; ks < 4; ks++)
            #pragma unroll
            for (int kk = 0; kk < 2; kk++) {
                bf16x8 a = af[ks * 2 + kk];
                #pragma unroll
                for (int l = 0; l < 2; l++) {
                    int jl = (wn * 2 + l) * 16 + lr;
                    bf16x8 bb = lds_frag(kbuf + ks * 4096, jl, kk, q);
                    sacc[t * 2 + l] = MFMA(a, bb, sacc[t * 2 + l]);
                }
            }
        __builtin_amdgcn_s_barrier();
    }

    #pragma unroll
    for (int s = 0; s < 10; s++) {
        int j = (s >> 1) * 64 + (wn * 2 + (s & 1)) * 16 + lr;
        float bia = sBias[j];
        #pragma unroll
        for (int r = 0; r < 4; r++) sacc[s][r] = sacc[s][r] * 0.0625f + bia;
    }
    #pragma unroll
    for (int r = 0; r < 4; r++) {
        float mx = -1e30f;
        #pragma unroll
        for (int s = 0; s < 10; s++) mx = fmaxf(mx, sacc[s][r]);
        mx = fmaxf(mx, __shfl_xor(mx, 1));
        mx = fmaxf(mx, __shfl_xor(mx, 2));
        mx = fmaxf(mx, __shfl_xor(mx, 4));
        mx = fmaxf(mx, __shfl_xor(mx, 8));
        if (lr == 0) sPm[wn][wm * 16 + q * 4 + r] = mx;
    }
    __syncthreads();   // no vmem outstanding here (K loop drained to 0)

    stage_swz(vbase, GP, 0 * 64, sKV[0], 32, w, 8, lane);

    #pragma unroll
    for (int r = 0; r < 4; r++) {
        int row = wm * 16 + q * 4 + r;
        float rm = fmaxf(sPm[0][row], sPm[1][row]);
        float ss = 0.0f;
        #pragma unroll
        for (int s = 0; s < 10; s++) {
            float e = __expf(sacc[s][r] - rm);
            sacc[s][r] = e;
            ss += e;
        }
        ss += __shfl_xor(ss, 1);
        ss += __shfl_xor(ss, 2);
        ss += __shfl_xor(ss, 4);
        ss += __shfl_xor(ss, 8);
        if (lr == 0) sPs[wn][row] = ss;
    }
    asm volatile("s_waitcnt lgkmcnt(0)" ::: "memory");
    __builtin_amdgcn_s_barrier();
    __builtin_amdgcn_sched_barrier(0);

    float invr[4];
    #pragma unroll
    for (int r = 0; r < 4; r++) {
        int row = wm * 16 + q * 4 + r;
        invr[r] = 1.0f / (sPs[0][row] + sPs[1][row]);
    }
    unsigned pk[10][2];
    #pragma unroll
    for (int s = 0; s < 10; s++) {
        pk[s][0] = (unsigned)f2bf(sacc[s][0] * invr[0]) |
                   ((unsigned)f2bf(sacc[s][1] * invr[1]) << 16);
        pk[s][1] = (unsigned)f2bf(sacc[s][2] * invr[2]) |
                   ((unsigned)f2bf(sacc[s][3] * invr[3]) << 16);
    }

    f32x4 oacc[8];
    #pragma unroll
    for (int n = 0; n < 8; n++) oacc[n] = {0.0f, 0.0f, 0.0f, 0.0f};

    #pragma unroll
    for (int c = 0; c < 5; c++) {
        if (c < 4) {
            stage_swz(vbase, GP, (c + 1) * 64, sKV[(c + 1) & 1], 32, w, 8, lane);
            asm volatile("s_waitcnt vmcnt(4)" ::: "memory");
        } else {
            asm volatile("s_waitcnt vmcnt(0)" ::: "memory");
        }
        __builtin_amdgcn_s_barrier();
        #pragma unroll
        for (int sl = 0; sl < 2; sl++) {
            int jl = (wn * 2 + sl) * 16 + lr;
            #pragma unroll
            for (int r = 0; r < 4; r++) {
                int row = wm * 16 + q * 4 + r;
                unsigned v = pk[c * 2 + sl][r >> 1];
                sPt[row * 72 + jl] = (u16)((r & 1) ? (v >> 16) : (v & 0xffffu));
            }
        }
        asm volatile("s_waitcnt lgkmcnt(0)" ::: "memory");
        __builtin_amdgcn_s_barrier();
        __builtin_amdgcn_sched_barrier(0);
        #pragma unroll
        for (int kk = 0; kk < 2; kk++) {
            bf16x8 a = *(const bf16x8*)(sPt + (wm * 16 + lr) * 72 + kk * 32 + lk);
            #pragma unroll
            for (int n = 0; n < 8; n++) {
                bf16x8 vv = lds_frag(sKV[c & 1], wn * 128 + n * 16 + lr, kk, q);
                oacc[n] = MFMA(a, vv, oacc[n]);
            }
        }
        __builtin_amdgcn_s_barrier();
    }

    #pragma unroll
    for (int n = 0; n < 8; n++) {
        int col = wn * 128 + n * 16 + lr;
        #pragma unroll
        for (int r = 0; r < 4; r++) {
            int row = wm * 16 + q * 4 + r;
            aob[((size_t)(b * GP + t0 + row)) * 256 + col] = f2bf(oacc[n][r]);
        }
    }
}

// ------------- head part 1 (wide): graph embed -> fc -> u[b] -------------
// 1024 threads: 16 g-stripes x 64 float4-cols. Serial chain 301 -> 19 iters.
__global__ __launch_bounds__(1024) void final1_kernel(
    const float* __restrict__ h, const float* __restrict__ obs,
    const float* __restrict__ w_fc, const float* __restrict__ w_pn,
    float* __restrict__ u)
{
    __shared__ float part[16][256];   // 16 KB
    __shared__ float vpart[16];
    __shared__ float ges[EE];
    __shared__ float fcs[EE];

    int b = blockIdx.x;
    int t = threadIdx.x;
    int c4 = (t & 63) * 4;
    int st = t >> 6;                  // 0..15

    float a0 = 0.0f, a1 = 0.0f, a2 = 0.0f, a3 = 0.0f, vl = 0.0f;
    for (int g = st; g < GG; g += 16) {
        float m = obs[((size_t)b * GG + g) * 9 + 8];
        float4 hv = *(const float4*)(h + ((size_t)b * GP + g) * EE + c4);
        a0 += hv.x * m; a1 += hv.y * m; a2 += hv.z * m; a3 += hv.w * m;
        vl += m;
    }
    part[st][c4 + 0] = a0; part[st][c4 + 1] = a1;
    part[st][c4 + 2] = a2; part[st][c4 + 3] = a3;
    if ((t & 63) == 0) vpart[st] = vl;
    __syncthreads();

    if (t < 256) {
        float s = 0.0f;
        #pragma unroll
        for (int i = 0; i < 16; i++) s += part[i][t];
        float vsum = 0.0f;
        #pragma unroll
        for (int i = 0; i < 16; i++) vsum += vpart[i];
        ges[t] = s / vsum;
    }
    __syncthreads();

    {
        int col = t & 255, kq = t >> 8;
        float fcp = 0.0f;
        for (int i = 0; i < 64; i++) {
            int kk = kq * 64 + i;
            fcp += ges[kk] * w_fc[kk * EE + col];
        }
        part[kq][col] = fcp;
    }
    __syncthreads();
    if (t < 256) fcs[t] = part[0][t] + part[1][t] + part[2][t] + part[3][t];
    __syncthreads();

    {
        int e = t & 255, kq = t >> 8;
        const float4* wp = reinterpret_cast<const float4*>(w_pn + (size_t)e * 3 * EE + kq * 64);
        float ua = 0.0f;
        #pragma unroll
        for (int i = 0; i < 16; i++) {
            float4 w = wp[i];
            int base = kq * 64 + i * 4;
            ua += w.x * fcs[base] + w.y * fcs[base + 1] +
                  w.z * fcs[base + 2] + w.w * fcs[base + 3];
        }
        part[kq][e] = ua;
    }
    __syncthreads();
    if (t < 256)
        u[(size_t)b * EE + t] = part[0][t] + part[1][t] + part[2][t] + part[3][t];
}

// ------------- head part 2: compat -> tanh clip -> masked softmax -------------
__global__ __launch_bounds__(128) void final2_kernel(
    const float* __restrict__ h, const float* __restrict__ obs,
    const float* __restrict__ u, float* __restrict__ out)
{
    int b = blockIdx.x;
    int t = threadIdx.x;
    __shared__ float us[EE];
    __shared__ float red[8];
    us[t]       = u[(size_t)b * EE + t];
    us[t + 128] = u[(size_t)b * EE + t + 128];
    __syncthreads();

    float logit = -INFINITY;
    float m = 0.0f;
    if (t < LHN) {
        int g = IHN + t;
        m = obs[((size_t)b * GG + g) * 9 + 8];
        const float4* hr = reinterpret_cast<const float4*>(h + ((size_t)b * GP + g) * EE);
        float c = 0.0f;
        for (int kk = 0; kk < EE / 4; kk++) {
            float4 hv = hr[kk];
            c += hv.x * us[kk * 4] + hv.y * us[kk * 4 + 1] +
                 hv.z * us[kk * 4 + 2] + hv.w * us[kk * 4 + 3];
        }
        c *= m;
        c *= 0.0625f;
        logit = tanhf(c) * 10.0f;
    }
    float bm = blockReduceMax(logit, red);
    float e  = (t < LHN) ? __expf(logit - bm) : 0.0f;
    float bs = blockReduceSum(e, red);
    float p  = e / bs;
    float masked = (t < LHN) ? (p * m + 1e-20f) : 0.0f;
    float bs2 = blockReduceSum(masked, red);
    if (t < LHN) out[(size_t)b * LHN + t] = masked / bs2;
}

extern "C" void kernel_launch(void* const* d_in, const int* in_sizes, int n_in,
                              void* d_out, int out_size, void* d_ws, size_t ws_size,
                              hipStream_t stream) {
    const float* obs   = (const float*)d_in[0];
    const float* wi1   = (const float*)d_in[1];
    const float* bi1   = (const float*)d_in[2];
    const float* wi2   = (const float*)d_in[3];
    const float* bi2   = (const float*)d_in[4];
    const float* wl1   = (const float*)d_in[5];
    const float* bl1   = (const float*)d_in[6];
    const float* wl2   = (const float*)d_in[7];
    const float* bl2   = (const float*)d_in[8];
    const float* wn1   = (const float*)d_in[9];
    const float* bn1   = (const float*)d_in[10];
    const float* wn2   = (const float*)d_in[11];
    const float* bn2   = (const float*)d_in[12];
    const float* e_wq  = (const float*)d_in[13];
    const float* e_wk  = (const float*)d_in[14];
    const float* e_wv  = (const float*)d_in[15];
    const float* e_wo  = (const float*)d_in[16];
    const float* e_wf1 = (const float*)d_in[17];
    const float* e_bf1 = (const float*)d_in[18];
    const float* e_wf2 = (const float*)d_in[19];
    const float* e_bf2 = (const float*)d_in[20];
    const float* w_pn  = (const float*)d_in[21];
    const float* w_fc  = (const float*)d_in[22];
    float* outp = (float*)d_out;

    // ---- compact workspace layout: 254,017,536 B total ----
    char* wsc = (char*)d_ws;
    float* h    = (float*)wsc;
    u16*   hb   = (u16*)(wsc + 83886080);
    u16*   qaob = (u16*)(wsc + 125829120);   // qb, later aob
    u16*   kb   = (u16*)(wsc + 167772160);
    u16*   vt   = (u16*)(wsc + 209715200);
    u16*   wT   = (u16*)(wsc + 251658240);
    float* ubuf = (float*)(wsc + 253755392);
    u16*   hidb = kb;  // overlays kb+vt (disjoint lifetime)

    prep_kernel<<<dim3(512, 12), 256, 0, stream>>>(e_wq, e_wk, e_wv, e_wo, e_wf1, e_wf2, wT);
    pad_kernel<<<BB, 256, 0, stream>>>(h, hb);
    embed_seg<ILN, IHN, 0><<<IHN * BB / 32, 256, 0, stream>>>(obs, wi1, bi1, wi2, bi2, h, hb);
    embed_seg<8, LHN, IHN><<<LHN * BB / 32, 256, 0, stream>>>(obs, wl1, bl1, wl2, bl2, h, hb);
    embed_seg<6, 1, IHN + LHN><<<BB / 32, 256, 0, stream>>>(obs, wn1, bn1, wn2, bn2, h, hb);

    const size_t WL = 524288;
    for (int l = 0; l < NL; l++) {
        u16* wqkvT = wT + l * WL;
        u16* woT   = wqkvT + 196608;
        u16* w1T   = wqkvT + 262144;
        u16* w2T   = wqkvT + 393216;
        const float* bf1 = e_bf1 + (size_t)l * FFH;
        const float* bf2 = e_bf2 + (size_t)l * EE;

        qkv_gemm<<<MT / 128, 512, 0, stream>>>(hb, wqkvT, qaob, kb, vt);
        attn_core<<<1280, 512, 0, stream>>>(qaob, kb, vt, obs, qaob);
        gemmln_kernel<4, 256, false><<<MT / 64, 512, 0, stream>>>(qaob, woT, nullptr, h, hb);
        ff1_gemm<<<MT / 128, 512, 0, stream>>>(hb, w1T, bf1, hidb);
        gemmln_kernel<8, 512, true><<<MT / 64, 512, 0, stream>>>(hidb, w2T, bf2, h, hb);
    }
    final1_kernel<<<BB, 1024, 0, stream>>>(h, obs, w_fc, w_pn, ubuf);
    final2_kernel<<<BB, 128, 0, stream>>>(h, obs, ubuf, outp);
}